// Round 3
// baseline (146.935 us; speedup 1.0000x reference)
//
#include <hip/hip_runtime.h>
#include <math.h>

#define NBATCH 32
#define S      49152
#define NF     24          // frames (2048 samples each)
#define NB     16          // biquads
#define NBLK   8           // blocks per batch  (R12: was 4 -- fill all 256 CUs)
#define CHUNK  8           // samples per thread (R12: was 16)
#define NCH    768         // threads per block
#define NWAVE  12          // waves per block
// 8 blocks per batch; block covers 768*8 = 6144 samples = 3 frames.
// R12: R9 structure (2 barriers/stage, wave-0 second level -- best measured at
// 74us) scaled to the FULL chip. R9/R10/R11 all landed 74-90us with half the
// CUs idle (128 blocks) and ~84% stall; R11's +0.9us of added VALU cost +12us
// of wall (15x amplification) -> latency-bound with only 3 waves/SIMD on half
// the chip. R12: 256 blocks x 12 waves = 1 block/CU everywhere, per-wave
// payload halved. Cross-block fold (now <=7 preds) is parallelized: lane j
// polls slot j (all polls in flight), then a 3-step shfl compose-scan folds
// them in order -- ~2 latency hops instead of 7 serial L2 round-trips.

__device__ __forceinline__ float clampf(float x, float lo, float hi) {
    return fminf(fmaxf(x, lo), hi);
}

// 8 named scalar signal registers -- guaranteed SSA (no alloca; R1-R4 showed
// the allocator pins VGPR and spills float arrays regardless of hints).
#define FOREACH_S(OP) \
    OP(s00) OP(s01) OP(s02) OP(s03) OP(s04) OP(s05) OP(s06) OP(s07)

#define DECL_S(x) float x;

// Phase A step: state only.  s' = T s + b*x
#define STEPA(x) { \
    const float n1_ = fmaf(t00, ic1, fmaf(t01, ic2, b0 * (x))); \
    const float n2_ = fmaf(t10, ic1, fmaf(t11, ic2, b1 * (x))); \
    ic1 = n1_; ic2 = n2_; }

// Phase C step: output + state.  y = c0*ic1 + c1*ic2 + c2*x, in place.
#define STEPC(x) { \
    const float y_  = fmaf(c0, ic1, fmaf(c1, ic2, c2 * (x))); \
    const float n1_ = fmaf(t00, ic1, fmaf(t01, ic2, b0 * (x))); \
    const float n2_ = fmaf(t10, ic1, fmaf(t11, ic2, b1 * (x))); \
    (x) = y_; ic1 = n1_; ic2 = n2_; }

__global__ __launch_bounds__(NCH, 3)
void biquad_chain_kernel(const float* __restrict__ audio,
                         const float* __restrict__ params,
                         float* __restrict__ out,
                         unsigned int* __restrict__ ws)
{
    __shared__ float sc[NB][NF][16];     // stride 16 -> float4-aligned reads
    __shared__ float sgain[2][NF];       // [0]=in gain, [1]=out gain
    __shared__ float4 saggM[NWAVE];      // wave aggregate matrices
    __shared__ float  saggC[NWAVE][2];   // wave aggregate constants
    __shared__ float  sv[NWAVE][2];      // per-wave incoming state

    const int t       = threadIdx.x;
    // XCD co-location swizzle: blockIdx = oct*32 + bt -> all 8 blocks of a
    // batch share XCD (bt & 7); 4 batches per XCD.
    const int bt      = blockIdx.x & 31;         // batch
    const int oct     = blockIdx.x >> 5;         // which eighth of the signal
    const int lane    = t & 63;
    const int wave    = t >> 6;
    const int frame   = oct * 3 + (wave >> 2);   // 4 waves per 2048-frame

    // ---------------- coefficient init (threads 0..383) ----------------
    if (t < NB * NF) {
        const int f  = t / NF;
        const int fr = t % NF;
        const float* P = params + (size_t)bt * 50 * NF;
        const float fn = P[(3 * f + 0) * NF + fr];
        const float gn = P[(3 * f + 1) * NF + fr];
        const float qn = P[(3 * f + 2) * NF + fr];

        float Q = __expf(-0.69314718f + qn * 3.4657359f);
        Q = clampf(Q, 0.1f, 100.0f);

        float lo, hi;
        int type;                        // 0 hp, 1 lp, 2 peak, 3 lowshelf, 4 highshelf
        if      (f == 0)  { lo = 20.0f;   hi = 500.0f;   type = 0; }
        else if (f == 15) { lo = 5000.0f; hi = 20000.0f; type = 1; }
        else if (f == 1)  { lo = 50.0f;   hi = 16000.0f; type = 3; }
        else if (f == 14) { lo = 50.0f;   hi = 16000.0f; type = 4; }
        else              { lo = 100.0f;  hi = 15000.0f; type = 2; }

        const float fc = __expf(__logf(lo) + fn * (__logf(hi) - __logf(lo)));
        float g_ = __tanf((float)M_PI * fc / 96000.0f);   // angle <= 0.655 rad, safe
        g_ = clampf(g_, 1e-6f, 100.0f);
        const float gdb = -24.0f + 48.0f * gn;

        float a1, a2, a3, m0, m1, m2;
        if (type == 0 || type == 1) {
            const float k = 1.0f / Q;
            a1 = 1.0f / (1.0f + g_ * (g_ + k)); a2 = g_ * a1; a3 = g_ * a2;
            if (type == 0) { m0 = 1.0f; m1 = -k;   m2 = -1.0f; }
            else           { m0 = 0.0f; m1 = 0.0f; m2 = 1.0f;  }
        } else if (type == 2) {
            const float A = __expf(gdb * (2.30258509f / 40.0f));
            const float k = (gdb >= 0.0f) ? 1.0f / (Q * A) : A / Q;
            a1 = 1.0f / (1.0f + g_ * (g_ + k)); a2 = g_ * a1; a3 = g_ * a2;
            m0 = 1.0f; m1 = k * (A * A - 1.0f); m2 = 0.0f;
        } else {
            const float A  = __expf(gdb * (2.30258509f / 40.0f));
            const float sA = sqrtf(A);
            const float k  = 1.0f / Q;
            float gs;
            if (type == 3) gs = (gdb >= 0.0f) ? g_ / sA : g_ * sA;
            else           gs = (gdb >= 0.0f) ? g_ * sA : g_ / sA;
            a1 = 1.0f / (1.0f + gs * (gs + k)); a2 = gs * a1; a3 = gs * a2;
            if (type == 3) { m0 = 1.0f;  m1 = k * (A - 1.0f);      m2 = A * A - 1.0f; }
            else           { m0 = A * A; m1 = k * (1.0f - A) * A;  m2 = 1.0f - A * A; }
        }

        // affine per-sample form: s' = T s + b*x ; y = c0*ic1 + c1*ic2 + c2*x
        const float q2  = a2 * a2 + a3;
        const float t00 = 2.0f * a1 - 1.0f;
        const float t01 = -2.0f * a2;
        const float t10 = 2.0f * a1 * a2;
        const float t11 = 1.0f - 2.0f * q2;
        const float b0  = 2.0f * a2;
        const float b1  = 2.0f * q2;
        const float c0  = a1 * (m1 + m2 * a2);
        const float c1  = m2 * (1.0f - q2) - m1 * a2;
        const float c2  = m0 + m1 * a2 + m2 * q2;

        // M = T^8 by 3 squarings (CHUNK=8)
        float u00 = t00, u01 = t01, u10 = t10, u11 = t11;
        #pragma unroll
        for (int i = 0; i < 3; i++) {
            const float n00 = u00 * u00 + u01 * u10;
            const float n01 = u00 * u01 + u01 * u11;
            const float n10 = u10 * u00 + u11 * u10;
            const float n11 = u10 * u01 + u11 * u11;
            u00 = n00; u01 = n01; u10 = n10; u11 = n11;
        }

        // layout for float4 reads:
        // [0-3]=t00,t01,t10,t11  [4-7]=b0,b1,c0,c1  [8-11]=c2,M00,M01,M10  [12]=M11
        sc[f][fr][0] = t00; sc[f][fr][1] = t01; sc[f][fr][2] = t10; sc[f][fr][3] = t11;
        sc[f][fr][4] = b0;  sc[f][fr][5] = b1;  sc[f][fr][6] = c0;  sc[f][fr][7] = c1;
        sc[f][fr][8] = c2;  sc[f][fr][9] = u00; sc[f][fr][10] = u01; sc[f][fr][11] = u10;
        sc[f][fr][12] = u11;
    }
    if (t >= 384 && t < 384 + 2 * NF) {
        const int idx = t - 384;
        const int which = idx / NF;     // 0 = in gain (row 48), 1 = out gain (row 49)
        const int fr    = idx % NF;
        const float* P = params + (size_t)bt * 50 * NF;
        const float p  = P[(48 + which) * NF + fr];
        const float db = -60.0f + 60.0f * p;
        sgain[which][fr] = __expf(db * (2.30258509f / 20.0f));
    }
    __syncthreads();

    // ---------------- load chunk (with input gain) ----------------
    FOREACH_S(DECL_S)
    {
        const float ing = sgain[0][frame];
        const float* base = audio + (size_t)bt * S
                          + (size_t)(oct * NCH + t) * CHUNK;
        float4 q;
        q = *(const float4*)(base + 0); s00 = q.x*ing; s01 = q.y*ing; s02 = q.z*ing; s03 = q.w*ing;
        q = *(const float4*)(base + 4); s04 = q.x*ing; s05 = q.y*ing; s06 = q.z*ing; s07 = q.w*ing;
    }

    // ---------------- 16 cascaded stages ----------------
    #pragma unroll 1
    for (int f = 0; f < NB; f++) {
        const float4 q0 = *(const float4*)&sc[f][frame][0];  // t00 t01 t10 t11
        const float4 q1 = *(const float4*)&sc[f][frame][4];  // b0 b1 c0 c1
        const float4 q2 = *(const float4*)&sc[f][frame][8];  // c2 M00 M01 M10
        const float  M11v = sc[f][frame][12];
        const float t00 = q0.x, t01 = q0.y, t10 = q0.z, t11 = q0.w;
        const float b0  = q1.x, b1  = q1.y, c0  = q1.z, c1  = q1.w;
        const float c2  = q2.x;

        // Phase A: zero-state run over own chunk -> affine constant
        float ic1 = 0.0f, ic2 = 0.0f;
        FOREACH_S(STEPA)

        // constants-only Kogge-Stone: all lanes share M=T^8, so step d
        // composes with wave-uniform M^d (register, squared in place).
        float Md00 = q2.y, Md01 = q2.z, Md10 = q2.w, Md11 = M11v;
        float Ac0 = ic1, Ac1 = ic2;
        #pragma unroll
        for (int d = 1; d < 64; d <<= 1) {
            const float lc0 = __shfl_up(Ac0, d);
            const float lc1 = __shfl_up(Ac1, d);
            if (lane >= d) {
                Ac0 = fmaf(Md00, lc0, fmaf(Md01, lc1, Ac0));
                Ac1 = fmaf(Md10, lc0, fmaf(Md11, lc1, Ac1));
            }
            const float n00 = Md00 * Md00 + Md01 * Md10;
            const float n01 = Md00 * Md01 + Md01 * Md11;
            const float n10 = Md10 * Md00 + Md11 * Md10;
            const float n11 = Md10 * Md01 + Md11 * Md11;
            Md00 = n00; Md01 = n01; Md10 = n10; Md11 = n11;
        }
        // Md = M^64 (wave aggregate matrix); Ac at lane 63 = aggregate const

        if (lane == 63) {
            saggM[wave] = make_float4(Md00, Md01, Md10, Md11);
            saggC[wave][0] = Ac0; saggC[wave][1] = Ac1;
        }
        __syncthreads();

        const unsigned int tag = (unsigned int)(f + 1);
        unsigned int* stagebase = ws + ((size_t)(bt * NB + f) * NBLK) * 8;

        // Second level on wave 0 only: scan 12 aggregates, publish block
        // aggregate, parallel-poll predecessors, distribute per-wave state v.
        if (wave == 0) {
            float G00 = 1.0f, G01 = 0.0f, G10 = 0.0f, G11 = 1.0f, Gc0 = 0.0f, Gc1 = 0.0f;
            if (lane < NWAVE) {
                const float4 m = saggM[lane];
                G00 = m.x; G01 = m.y; G10 = m.z; G11 = m.w;
                Gc0 = saggC[lane][0]; Gc1 = saggC[lane][1];
            }
            #pragma unroll
            for (int d = 1; d < 16; d <<= 1) {
                const float l00 = __shfl_up(G00, d);
                const float l01 = __shfl_up(G01, d);
                const float l10 = __shfl_up(G10, d);
                const float l11 = __shfl_up(G11, d);
                const float lc0 = __shfl_up(Gc0, d);
                const float lc1 = __shfl_up(Gc1, d);
                if (lane >= d && lane < NWAVE) {
                    const float n00 = G00 * l00 + G01 * l10;
                    const float n01 = G00 * l01 + G01 * l11;
                    const float n10 = G10 * l00 + G11 * l10;
                    const float n11 = G10 * l01 + G11 * l11;
                    const float nc0 = G00 * lc0 + G01 * lc1 + Gc0;
                    const float nc1 = G10 * lc0 + G11 * lc1 + Gc1;
                    G00 = n00; G01 = n01; G10 = n10; G11 = n11;
                    Gc0 = nc0; Gc1 = nc1;
                }
            }

            // publish block aggregate (inclusive at lane 11) ASAP
            if (oct < NBLK - 1 && lane == NWAVE - 1) {
                unsigned int* slot = stagebase + oct * 8;
                float* dp = (float*)(slot + 1);
                __hip_atomic_store(&dp[0], G00, __ATOMIC_RELAXED, __HIP_MEMORY_SCOPE_AGENT);
                __hip_atomic_store(&dp[1], G01, __ATOMIC_RELAXED, __HIP_MEMORY_SCOPE_AGENT);
                __hip_atomic_store(&dp[2], G10, __ATOMIC_RELAXED, __HIP_MEMORY_SCOPE_AGENT);
                __hip_atomic_store(&dp[3], G11, __ATOMIC_RELAXED, __HIP_MEMORY_SCOPE_AGENT);
                __hip_atomic_store(&dp[4], Gc0, __ATOMIC_RELAXED, __HIP_MEMORY_SCOPE_AGENT);
                __hip_atomic_store(&dp[5], Gc1, __ATOMIC_RELAXED, __HIP_MEMORY_SCOPE_AGENT);
                __hip_atomic_store(slot, tag, __ATOMIC_RELEASE, __HIP_MEMORY_SCOPE_AGENT);
            }

            // exclusive wave prefix
            float P00 = __shfl_up(G00, 1);
            float P01 = __shfl_up(G01, 1);
            float P10 = __shfl_up(G10, 1);
            float P11 = __shfl_up(G11, 1);
            float Pc0 = __shfl_up(Gc0, 1);
            float Pc1 = __shfl_up(Gc1, 1);
            if (lane == 0) { P00 = 1.0f; P01 = 0.0f; P10 = 0.0f; P11 = 1.0f; Pc0 = 0.0f; Pc1 = 0.0f; }

            // block incoming state S0: lanes 0..oct-1 poll pred slots in
            // PARALLEL, then 3-step shfl compose-scan folds them in order.
            float S0x = 0.0f, S0y = 0.0f;
            if (oct > 0) {
                float A00 = 1.0f, A01 = 0.0f, A10 = 0.0f, A11 = 1.0f;
                float Acx = 0.0f, Acy = 0.0f;
                if (lane < oct) {
                    unsigned int* slot = stagebase + lane * 8;
                    while (__hip_atomic_load(slot, __ATOMIC_ACQUIRE, __HIP_MEMORY_SCOPE_AGENT) != tag) {
                        __builtin_amdgcn_s_sleep(1);
                    }
                    const float* dp = (const float*)(slot + 1);
                    A00 = __hip_atomic_load(&dp[0], __ATOMIC_RELAXED, __HIP_MEMORY_SCOPE_AGENT);
                    A01 = __hip_atomic_load(&dp[1], __ATOMIC_RELAXED, __HIP_MEMORY_SCOPE_AGENT);
                    A10 = __hip_atomic_load(&dp[2], __ATOMIC_RELAXED, __HIP_MEMORY_SCOPE_AGENT);
                    A11 = __hip_atomic_load(&dp[3], __ATOMIC_RELAXED, __HIP_MEMORY_SCOPE_AGENT);
                    Acx = __hip_atomic_load(&dp[4], __ATOMIC_RELAXED, __HIP_MEMORY_SCOPE_AGENT);
                    Acy = __hip_atomic_load(&dp[5], __ATOMIC_RELAXED, __HIP_MEMORY_SCOPE_AGENT);
                }
                // ordered compose-scan over lanes 0..oct-1 (oct <= 7 -> 3 steps)
                #pragma unroll
                for (int d = 1; d < 8; d <<= 1) {
                    const float l00 = __shfl_up(A00, d);
                    const float l01 = __shfl_up(A01, d);
                    const float l10 = __shfl_up(A10, d);
                    const float l11 = __shfl_up(A11, d);
                    const float lcx = __shfl_up(Acx, d);
                    const float lcy = __shfl_up(Acy, d);
                    if (lane >= d && lane < oct) {
                        const float n00 = A00 * l00 + A01 * l10;
                        const float n01 = A00 * l01 + A01 * l11;
                        const float n10 = A10 * l00 + A11 * l10;
                        const float n11 = A10 * l01 + A11 * l11;
                        const float ncx = fmaf(A00, lcx, fmaf(A01, lcy, Acx));
                        const float ncy = fmaf(A10, lcx, fmaf(A11, lcy, Acy));
                        A00 = n00; A01 = n01; A10 = n10; A11 = n11;
                        Acx = ncx; Acy = ncy;
                    }
                }
                // composition applied to zero initial state = its constant
                S0x = __shfl(Acx, oct - 1);
                S0y = __shfl(Acy, oct - 1);
            }

            // per-wave incoming state v = P(S0); lanes 0..11 write to LDS
            if (lane < NWAVE) {
                sv[lane][0] = fmaf(P00, S0x, fmaf(P01, S0y, Pc0));
                sv[lane][1] = fmaf(P10, S0x, fmaf(P11, S0y, Pc1));
            }
        }
        __syncthreads();

        const float vx = sv[wave][0];
        const float vy = sv[wave][1];

        // lane-exclusive constants
        float ce0 = __shfl_up(Ac0, 1);
        float ce1 = __shfl_up(Ac1, 1);
        if (lane == 0) { ce0 = 0.0f; ce1 = 0.0f; }

        // w = M^lane * v via in-register binary exponentiation (powers of the
        // same M commute, order irrelevant). 0 DS ops.
        float w0 = vx, w1 = vy;
        float p00 = q2.y, p01 = q2.z, p10 = q2.w, p11 = M11v;
        #pragma unroll
        for (int b = 0; b < 6; b++) {
            if (lane & (1 << b)) {
                const float nw0 = fmaf(p00, w0, p01 * w1);
                const float nw1 = fmaf(p10, w0, p11 * w1);
                w0 = nw0; w1 = nw1;
            }
            if (b < 5) {
                const float n00 = p00 * p00 + p01 * p10;
                const float n01 = p00 * p01 + p01 * p11;
                const float n10 = p10 * p00 + p11 * p10;
                const float n11 = p10 * p01 + p11 * p11;
                p00 = n00; p01 = n01; p10 = n10; p11 = n11;
            }
        }
        ic1 = w0 + ce0;
        ic2 = w1 + ce1;

        // Phase C: true run from incoming state, write outputs in place
        FOREACH_S(STEPC)
    }

    // ---------------- store (with output gain) ----------------
    {
        const float og = sgain[1][frame];
        float* base = out + (size_t)bt * S + (size_t)(oct * NCH + t) * CHUNK;
        float4 q;
        q.x = s00*og; q.y = s01*og; q.z = s02*og; q.w = s03*og; *(float4*)(base + 0) = q;
        q.x = s04*og; q.y = s05*og; q.z = s06*og; q.w = s07*og; *(float4*)(base + 4) = q;
    }
}

extern "C" void kernel_launch(void* const* d_in, const int* in_sizes, int n_in,
                              void* d_out, int out_size, void* d_ws, size_t ws_size,
                              hipStream_t stream)
{
    const float* audio  = (const float*)d_in[0];
    const float* params = (const float*)d_in[1];
    float* out = (float*)d_out;
    unsigned int* ws = (unsigned int*)d_ws;
    biquad_chain_kernel<<<NBLK * NBATCH, NCH, 0, stream>>>(audio, params, out, ws);
}